// Round 1
// baseline (184.673 us; speedup 1.0000x reference)
//
#include <hip/hip_runtime.h>
#include <stdint.h>

#define NN 8192      // nodes
#define FF 512       // feature dim
#define HH 64        // hidden
#define CC 10        // classes
#define EE 262144    // edges
#define NTR 512      // train nodes
#define ALPHA_NS 0.2f
#define HASH_BITS 19
#define HASH_CAP (1u << HASH_BITS)
#define HASH_MASK (HASH_CAP - 1u)
#define EMPTY_KEY 0xFFFFFFFFu

__device__ __forceinline__ float dot4(float4 a, float4 b){
    return a.x*b.x + a.y*b.y + a.z*b.z + a.w*b.w;
}

// v0[f] = sum_h W[h][f]*a[h] ; v1[f] = sum_h W[h][f]*a[HH+h]
__global__ void k_v01(const float* __restrict__ W, const float* __restrict__ a,
                      float* __restrict__ v01){
    int f = blockIdx.x*blockDim.x + threadIdx.x;
    if (f >= FF) return;
    float acc0 = 0.f, acc1 = 0.f;
    for (int hh = 0; hh < HH; ++hh){
        float w = W[hh*FF + f];
        acc0 += w * a[hh];
        acc1 += w * a[HH + hh];
    }
    v01[f] = acc0;
    v01[FF + f] = acc1;
}

// wave per row: s_src[r] = h[r]·v0 ; s_dst[r] = h[r]·v1
__global__ void k_sdots(const float* __restrict__ h, const float* __restrict__ v01,
                        float* __restrict__ s_src, float* __restrict__ s_dst){
    int row = blockIdx.x*4 + (threadIdx.x >> 6);
    int lane = threadIdx.x & 63;
    const float4* hr = (const float4*)(h + (size_t)row*FF);
    const float4* v0 = (const float4*)v01;
    const float4* v1 = (const float4*)(v01 + FF);
    float4 x0 = hr[lane*2], x1 = hr[lane*2+1];
    float a0 = dot4(x0, v0[lane*2]) + dot4(x1, v0[lane*2+1]);
    float a1 = dot4(x0, v1[lane*2]) + dot4(x1, v1[lane*2+1]);
    #pragma unroll
    for (int off = 32; off >= 1; off >>= 1){
        a0 += __shfl_xor(a0, off);
        a1 += __shfl_xor(a1, off);
    }
    if (lane == 0){ s_src[row] = a0; s_dst[row] = a1; }
}

// FW[r][c] = features[r] · W1[c]
__global__ void k_fw(const float* __restrict__ feat, const float* __restrict__ W1,
                     float* __restrict__ FW){
    int row = blockIdx.x*4 + (threadIdx.x >> 6);
    int lane = threadIdx.x & 63;
    const float4* fr = (const float4*)(feat + (size_t)row*FF);
    float4 x0 = fr[lane*2], x1 = fr[lane*2+1];
    float acc[CC];
    #pragma unroll
    for (int c = 0; c < CC; ++c){
        const float4* wr = (const float4*)(W1 + c*FF);
        acc[c] = dot4(x0, wr[lane*2]) + dot4(x1, wr[lane*2+1]);
    }
    #pragma unroll
    for (int c = 0; c < CC; ++c){
        float r = acc[c];
        #pragma unroll
        for (int off = 32; off >= 1; off >>= 1) r += __shfl_xor(r, off);
        acc[c] = r;
    }
    if (lane == 0){
        #pragma unroll
        for (int c = 0; c < CC; ++c) FW[row*CC + c] = acc[c];
    }
}

// class frequencies over train set + train-node marker
__global__ void k_cvec(const int* __restrict__ idx_train, const int* __restrict__ labels,
                       float* __restrict__ cvec, uint32_t* __restrict__ mark){
    __shared__ int hist[CC];
    if (threadIdx.x < CC) hist[threadIdx.x] = 0;
    __syncthreads();
    for (int t = threadIdx.x; t < NTR; t += blockDim.x){
        int node = idx_train[t];
        mark[node] = 1u;
        atomicAdd(&hist[labels[node]], 1);
    }
    __syncthreads();
    if (threadIdx.x < CC) cvec[threadIdx.x] = (float)hist[threadIdx.x] / (float)NTR;
}

// per-edge: hash-dedup (set semantics; value is pair-unique so winner is irrelevant),
// owner computes e, accumulates row-sum s1[src], counts incoming degree cnt[dst]
__global__ void k_edges(const int* __restrict__ ei, const float* __restrict__ s_src,
                        const float* __restrict__ s_dst, uint32_t* __restrict__ hkeys,
                        float* __restrict__ e_val, float* __restrict__ s1,
                        uint32_t* __restrict__ cnt){
    int k = blockIdx.x*blockDim.x + threadIdx.x;
    if (k >= EE) return;
    int src = ei[k], dst = ei[EE + k];
    uint32_t key = ((uint32_t)src << 13) | (uint32_t)dst;
    uint32_t slot = (key * 2654435761u) >> (32 - HASH_BITS);
    bool owner = false;
    while (true){
        uint32_t prev = atomicCAS(&hkeys[slot], EMPTY_KEY, key);
        if (prev == EMPTY_KEY){ owner = true; break; }
        if (prev == key) break;   // duplicate pair, same value -> drop
        slot = (slot + 1u) & HASH_MASK;
    }
    if (owner){
        float z = s_src[src] + s_dst[dst];
        z = (z >= 0.f) ? z : ALPHA_NS * z;
        float e = expf(z);
        e_val[k] = e;
        atomicAdd(&s1[src], e);
        atomicAdd(&cnt[dst], 1u);
    } else {
        e_val[k] = -1.0f;
    }
}

// exclusive scan of incoming degrees (incl. self-loop for zero-out-degree rows)
__global__ void k_scan(const uint32_t* __restrict__ cnt, const float* __restrict__ s1,
                       uint32_t* __restrict__ offs){
    __shared__ uint32_t part[1024];
    int t = threadIdx.x;
    uint32_t local[8];
    uint32_t sum = 0;
    #pragma unroll
    for (int i = 0; i < 8; ++i){
        int idx = t*8 + i;
        uint32_t v = cnt[idx] + (s1[idx] == 0.0f ? 1u : 0u);
        local[i] = v; sum += v;
    }
    part[t] = sum;
    __syncthreads();
    for (int off = 1; off < 1024; off <<= 1){
        uint32_t v = (t >= off) ? part[t - off] : 0u;
        __syncthreads();
        part[t] += v;
        __syncthreads();
    }
    uint32_t base = (t > 0) ? part[t-1] : 0u;
    #pragma unroll
    for (int i = 0; i < 8; ++i){
        offs[t*8 + i] = base;
        base += local[i];
    }
    if (t == 1023) offs[NN] = base;
}

// fill CSC (by dst): normalized weights e/s1[src]; self-loops w=1 for zero rows
__global__ void k_fill(const int* __restrict__ ei, const float* __restrict__ e_val,
                       const float* __restrict__ s1, const uint32_t* __restrict__ offs,
                       uint32_t* __restrict__ fillc, uint32_t* __restrict__ csc_src,
                       float* __restrict__ csc_w){
    int k = blockIdx.x*blockDim.x + threadIdx.x;
    if (k < EE){
        float e = e_val[k];
        if (e >= 0.f){
            int src = ei[k], dst = ei[EE + k];
            uint32_t pos = offs[dst] + atomicAdd(&fillc[dst], 1u);
            csc_src[pos] = (uint32_t)src;
            csc_w[pos] = e / s1[src];
        }
    } else {
        int i = k - EE;
        if (i < NN && s1[i] == 0.0f){
            uint32_t pos = offs[i] + atomicAdd(&fillc[i], 1u);
            csc_src[pos] = (uint32_t)i;
            csc_w[pos] = 1.0f;
        }
    }
}

// Db (= b since d≈1) and ut after t=1 (ut1 = Db since ut0 = 0)
__global__ void k_db(const int* __restrict__ labels, const uint32_t* __restrict__ mark,
                     const float* __restrict__ cvec, float* __restrict__ Db,
                     float* __restrict__ ua){
    int g = blockIdx.x*blockDim.x + threadIdx.x;
    if (g >= NN*CC) return;
    int i = g / CC, c = g - i*CC;
    float v = 0.f;
    if (mark[i]) v = ((labels[i] == c) ? 1.0f : 0.0f) - cvec[c];
    Db[g] = v;
    ua[g] = v;
}

// one diffusion step: uout[i,:] = sum_{p in CSC row i} w[p]*uin[src[p],:] + Db[i,:] (+FW)
__global__ void k_spmv(const uint32_t* __restrict__ offs, const uint32_t* __restrict__ csrc,
                       const float* __restrict__ cw, const float* __restrict__ uin,
                       const float* __restrict__ Db, const float* __restrict__ FW,
                       float* __restrict__ uout){
    int row = blockIdx.x*4 + (threadIdx.x >> 6);
    int lane = threadIdx.x & 63;
    uint32_t s = offs[row], e = offs[row+1];
    float acc[CC];
    #pragma unroll
    for (int c = 0; c < CC; ++c) acc[c] = 0.f;
    for (uint32_t p = s + lane; p < e; p += 64){
        uint32_t src = csrc[p];
        float w = cw[p];
        const float2* u2 = (const float2*)(uin + (size_t)src*CC);
        #pragma unroll
        for (int q = 0; q < 5; ++q){
            float2 v = u2[q];
            acc[2*q]   += w * v.x;
            acc[2*q+1] += w * v.y;
        }
    }
    #pragma unroll
    for (int c = 0; c < CC; ++c){
        float r = acc[c];
        #pragma unroll
        for (int off = 32; off >= 1; off >>= 1) r += __shfl_xor(r, off);
        acc[c] = r;
    }
    if (lane == 0){
        const float* db = Db + row*CC;
        float* o = uout + row*CC;
        if (FW){
            const float* fw = FW + row*CC;
            #pragma unroll
            for (int c = 0; c < CC; ++c) o[c] = acc[c] + db[c] + fw[c];
        } else {
            #pragma unroll
            for (int c = 0; c < CC; ++c) o[c] = acc[c] + db[c];
        }
    }
}

extern "C" void kernel_launch(void* const* d_in, const int* in_sizes, int n_in,
                              void* d_out, int out_size, void* d_ws, size_t ws_size,
                              hipStream_t stream){
    const float* h    = (const float*)d_in[0];
    const float* W    = (const float*)d_in[1];
    const float* a    = (const float*)d_in[2];
    const float* W1   = (const float*)d_in[3];
    const float* feat = (const float*)d_in[4];
    const int* ei     = (const int*)d_in[5];
    const int* idx_tr = (const int*)d_in[6];
    const int* labels = (const int*)d_in[7];
    float* out = (float*)d_out;

    char* wsp = (char*)d_ws;
    auto alloc = [&](size_t bytes)->void*{
        void* p = (void*)wsp;
        wsp += (bytes + 255) & ~(size_t)255;
        return p;
    };
    uint32_t* hkeys  = (uint32_t*)alloc((size_t)HASH_CAP*4);
    float*    s1     = (float*)   alloc(NN*4);
    uint32_t* cnt    = (uint32_t*)alloc(NN*4);
    uint32_t* offs   = (uint32_t*)alloc((NN+1)*4);
    uint32_t* fillc  = (uint32_t*)alloc(NN*4);
    uint32_t* mark   = (uint32_t*)alloc(NN*4);
    float*    e_val  = (float*)   alloc((size_t)EE*4);
    uint32_t* csrc   = (uint32_t*)alloc((size_t)(EE+NN)*4);
    float*    cw     = (float*)   alloc((size_t)(EE+NN)*4);
    float*    v01    = (float*)   alloc(2*FF*4);
    float*    s_src  = (float*)   alloc(NN*4);
    float*    s_dst  = (float*)   alloc(NN*4);
    float*    FW     = (float*)   alloc((size_t)NN*CC*4);
    float*    cvec   = (float*)   alloc(CC*4);
    float*    Db     = (float*)   alloc((size_t)NN*CC*4);
    float*    ua     = (float*)   alloc((size_t)NN*CC*4);
    float*    ub     = (float*)   alloc((size_t)NN*CC*4);

    hipMemsetAsync(hkeys, 0xFF, (size_t)HASH_CAP*4, stream);
    hipMemsetAsync(s1,    0, NN*4, stream);
    hipMemsetAsync(cnt,   0, NN*4, stream);
    hipMemsetAsync(fillc, 0, NN*4, stream);
    hipMemsetAsync(mark,  0, NN*4, stream);

    k_v01  <<<1, FF, 0, stream>>>(W, a, v01);
    k_sdots<<<NN/4, 256, 0, stream>>>(h, v01, s_src, s_dst);
    k_fw   <<<NN/4, 256, 0, stream>>>(feat, W1, FW);
    k_cvec <<<1, 512, 0, stream>>>(idx_tr, labels, cvec, mark);
    k_edges<<<EE/256, 256, 0, stream>>>(ei, s_src, s_dst, hkeys, e_val, s1, cnt);
    k_scan <<<1, 1024, 0, stream>>>(cnt, s1, offs);
    k_fill <<<(EE+NN)/256, 256, 0, stream>>>(ei, e_val, s1, offs, fillc, csrc, cw);
    k_db   <<<(NN*CC)/256, 256, 0, stream>>>(labels, mark, cvec, Db, ua);

    float* cur = ua;
    float* nxt = ub;
    for (int t = 2; t <= 10; ++t){
        float* dst = (t == 10) ? out : nxt;
        const float* fwp = (t == 7) ? FW : nullptr;
        k_spmv<<<NN/4, 256, 0, stream>>>(offs, csrc, cw, cur, Db, fwp, dst);
        float* tmp = cur; cur = dst; nxt = tmp;
    }
}